// Round 6
// baseline (240.412 us; speedup 1.0000x reference)
//
#include <hip/hip_runtime.h>
#include <hip/hip_bf16.h>

#define NB   4
#define MD   2048
#define KD   2048
#define ND   2048

// fallback (fused) kernel tile
#define BM   128
#define BN   128

typedef short bf16x8 __attribute__((ext_vector_type(8)));
typedef float f32x4  __attribute__((ext_vector_type(4)));
typedef unsigned int u32;

#define MFMA16(a, b, c) __builtin_amdgcn_mfma_f32_16x16x32_bf16(a, b, c, 0, 0, 0)
#define BAR()    __builtin_amdgcn_s_barrier()
#define PRIO(n)  __builtin_amdgcn_s_setprio(n)
#define WAITV(n) asm volatile("s_waitcnt vmcnt(" #n ")" ::: "memory")
#define SCHEDB() __builtin_amdgcn_sched_barrier(0)

// pack two fp32 -> one dword of 2 bf16 (RNE)
__device__ __forceinline__ unsigned pk2(float lo, float hi) {
    union { __hip_bfloat162 h2; unsigned u; } c;
    c.h2 = __float22bfloat162_rn(make_float2(lo, hi));
    return c.u;
}

__device__ __forceinline__ void gload_lds16(const void* g, void* l) {
    __builtin_amdgcn_global_load_lds(
        (const __attribute__((address_space(1))) u32*)g,
        (__attribute__((address_space(3))) u32*)l,
        16, 0, 0);
}

// ---- Phase 1 (fused): A fp32->bf16 cast (8 elem/thread)  +  B -> BT bf16 ----
#define NCAST ((NB * MD * KD / 8) / 256)   // 8192 cast blocks (uint4 out/thread)

__global__ __launch_bounds__(256) void prep_kernel(
    const float* __restrict__ A, const float* __restrict__ B,
    unsigned short* __restrict__ Abf, unsigned short* __restrict__ BT)
{
    __shared__ float t[64][65];   // transpose tile; +1 pad -> <=2-way conflicts (free)
    const int tid = threadIdx.x;

    if (blockIdx.x < NCAST) {
        const size_t idx = (size_t)blockIdx.x * 256 + tid;   // uint4 (8 bf16) index
        const float4 v0 = ((const float4*)A)[2 * idx];
        const float4 v1 = ((const float4*)A)[2 * idx + 1];
        uint4 w;
        w.x = pk2(v0.x, v0.y); w.y = pk2(v0.z, v0.w);
        w.z = pk2(v1.x, v1.y); w.w = pk2(v1.z, v1.w);
        ((uint4*)Abf)[idx] = w;
        return;
    }
    const int bx  = blockIdx.x - NCAST;      // 0..4095
    const int b   = bx >> 10;                // batch (1024 tiles per batch)
    const int rem = bx & 1023;
    const int k0  = (rem & 31) * 64;
    const int n0  = (rem >> 5) * 64;

    const float* Bb = B + (size_t)b * KD * ND;
    const int rk = tid >> 4;                 // 0..15, +16/pass
    const int rn = (tid & 15) * 4;
    #pragma unroll
    for (int p = 0; p < 4; ++p) {
        const int kl = p * 16 + rk;
        const float4 v = *(const float4*)(Bb + (size_t)(k0 + kl) * ND + n0 + rn);
        t[kl][rn + 0] = v.x; t[kl][rn + 1] = v.y;
        t[kl][rn + 2] = v.z; t[kl][rn + 3] = v.w;
    }
    __syncthreads();
    const int wn = tid >> 2;                 // 0..63 (owns column n)
    const int wk = (tid & 3) * 16;           // 16 consecutive k
    float f[16];
    #pragma unroll
    for (int j = 0; j < 16; ++j) f[j] = t[wk + j][wn];
    uint4 w0, w1;
    w0.x = pk2(f[0], f[1]);   w0.y = pk2(f[2], f[3]);
    w0.z = pk2(f[4], f[5]);   w0.w = pk2(f[6], f[7]);
    w1.x = pk2(f[8], f[9]);   w1.y = pk2(f[10], f[11]);
    w1.z = pk2(f[12], f[13]); w1.w = pk2(f[14], f[15]);
    unsigned short* dst = BT + (size_t)b * ND * KD + (size_t)(n0 + wn) * KD + k0 + wk;
    *(uint4*)(dst) = w0;
    *(uint4*)(dst + 8) = w1;
}

// ---------------------------------------------------------------------------
// Phase 2 (round 6): 256x256 tile, 8 waves (2M x 4N), BK=32, 4-buffer LDS
// ring, cross-tile software pipeline.
//
// R5 post-mortem: measured 151 k cyc/CU = MFMA 79.5 k + LDS-read 70.6 k --
// the two pipes run SERIALLY (bulk-synchronous phases; all waves read, then
// all MFMA). R6 decouples them: body(t) issues tile t+1's 12 frag reads
// (into the other register set) BEFORE tile t's 32-MFMA cluster; with 2
// waves/SIMD interleaving, the LDS pipe streams under the matrix pipe.
//   body(t): vmcnt(0)        ; drains stage(t+1), issued 1 body (~1400cy) ago
//            barrier         ; all waves' stage(t+1) now visible
//            reads(t+1)      ; 12 ds_read_b128 -> F[(t+1)&1]
//            stage(t+2)      ; 4 gload_lds into ring buf (t+2)&3
//            MFMA(t)         ; 32 MFMA on F[t&1] (read last body)
// Ledger: stage(t+2) targets the buffer last read at tile t-2 (2 barriers
// back); reads(t+1) follow the drain of stage(t+1) (per-wave vmcnt +
// barrier join => all waves' loads visible). Compiler's conservative
// vmcnt-before-ds_read lands with 0 outstanding -> no-op (R4 lesson).
// LDS layout per buffer (16 KB, 256 rows x 32 k): row pairs share a 128-B
// line ([line][half][4 slots]); physical slot = q ^ (line&3). Frag reads:
// 16 lanes -> 2 half-groups x 4 slots = 2-way bank alias (free, m136).
// gload dest stays linear (tid*16); source k pre-swizzled (rule #21).
// Keeps: XCD-bijective swizzle (FETCH 49 MB), setprio, m89 C/D epilogue.
// ---------------------------------------------------------------------------

#define READS(fA, fB, c) do {                                                \
    _Pragma("unroll")                                                        \
    for (int n_ = 0; n_ < 4; ++n_)                                           \
        fB[n_] = *(const bf16x8*)(ldsBc + (c) * 16384 + bOff + n_ * 1024);   \
    _Pragma("unroll")                                                        \
    for (int m_ = 0; m_ < 8; ++m_)                                           \
        fA[m_] = *(const bf16x8*)(ldsAc + (c) * 16384 + aOff + m_ * 1024);   \
} while (0)

#define STAGE(c, tile) do {                                                  \
    _Pragma("unroll")                                                        \
    for (int rr_ = 0; rr_ < 2; ++rr_) {                                      \
        gload_lds16(Abase + (size_t)(s_row2 + 128 * rr_) * KD                \
                          + (tile) * 32 + s_k,                               \
                    (char*)&LdsA[0][0] + (c) * 16384 + rr_ * 8192 + tid * 16);\
        gload_lds16(Bbase + (size_t)(s_row2 + 128 * rr_) * KD                \
                          + (tile) * 32 + s_k,                               \
                    (char*)&LdsB[0][0] + (c) * 16384 + rr_ * 8192 + tid * 16);\
    }                                                                        \
} while (0)

#define MFMAC(fA, fB) do {                                                   \
    PRIO(1);                                                                 \
    _Pragma("unroll")                                                        \
    for (int m_ = 0; m_ < 8; ++m_)                                           \
        _Pragma("unroll")                                                    \
        for (int n_ = 0; n_ < 4; ++n_)                                       \
            acc[m_][n_] = MFMA16(fA[m_], fB[n_], acc[m_][n_]);               \
    PRIO(0);                                                                 \
} while (0)

#define NOSTG ((void)0)

#define BODY(fAn, fBn, cn, fAc, fBc, STG) do {                               \
    WAITV(0); BAR();                                                         \
    READS(fAn, fBn, cn);                                                     \
    SCHEDB();                                                                \
    STG;                                                                     \
    SCHEDB();                                                                \
    MFMAC(fAc, fBc);                                                         \
} while (0)

__global__ __launch_bounds__(512, 2) void gemm256_kernel(
    const unsigned short* __restrict__ Abf, const unsigned short* __restrict__ BT,
    float* __restrict__ C)
{
    __shared__ __align__(16) unsigned short LdsA[4][8192];   // 64 KB ring (A)
    __shared__ __align__(16) unsigned short LdsB[4][8192];   // 64 KB ring (B)

    const int tid = threadIdx.x;

    // XCD-bijective chunked swizzle: 256 wgs, 8 XCDs, 32 wgs/XCD.
    const int wg    = blockIdx.x;
    const int lin   = ((wg & 7) << 5) | (wg >> 3);
    const int batch = lin >> 6;
    const int rem   = lin & 63;
    const int row0  = (rem >> 3) * 256;
    const int col0  = (rem & 7) * 256;

    const unsigned short* __restrict__ Abase =
        Abf + (size_t)batch * MD * KD + (size_t)row0 * KD;
    const unsigned short* __restrict__ Bbase =
        BT  + (size_t)batch * ND * KD + (size_t)col0 * KD;
    float* __restrict__ Cbase =
        C + (size_t)batch * MD * ND + (size_t)row0 * ND + col0;

    const int wave = tid >> 6;
    const int lane = tid & 63;
    const int q    = lane >> 4;          // 0..3 (k-slot within 32-k row)
    const int r    = lane & 15;          // 0..15
    const int wm   = (wave >> 2) * 128;  // 0 / 128
    const int wn   = (wave & 3)  * 64;   // 0,64,128,192

    // staging geometry: per round 512 thr x 16 B = 128 rows (paired) x 64 B
    const int s_row2 = ((tid >> 3) << 1) | ((tid >> 2) & 1);     // row in round
    const int s_k    = ((tid & 3) ^ ((tid >> 3) & 3)) << 3;      // pre-swz src k

    // frag-read byte offsets (row pair layout + slot XOR swizzle)
    const int R0A  = wm + r;
    const int aOff = (R0A >> 1) * 128 + (R0A & 1) * 64
                   + ((q ^ ((R0A >> 1) & 3)) * 16);              // +m*1024
    const int R0B  = wn + r;
    const int bOff = (R0B >> 1) * 128 + (R0B & 1) * 64
                   + ((q ^ ((R0B >> 1) & 3)) * 16);              // +n*1024

    const char* ldsAc = (const char*)&LdsA[0][0];
    const char* ldsBc = (const char*)&LdsB[0][0];

    f32x4 acc[8][4];
    #pragma unroll
    for (int m = 0; m < 8; ++m)
        #pragma unroll
        for (int n = 0; n < 4; ++n)
            acc[m][n] = (f32x4){0.f, 0.f, 0.f, 0.f};

    bf16x8 fA0[8], fB0[4], fA1[8], fB1[4];   // two named frag sets (rule #20)

    // prologue: tiles 0,1 staged; tile0 frags read
    STAGE(0, 0);
    STAGE(1, 1);
    WAITV(4); BAR();          // retire stage(0), keep stage(1) in flight
    READS(fA0, fB0, 0);

    for (int j = 0; j < 15; ++j) {           // tiles t=4j .. 4j+3 (t <= 59)
        const int t = j * 4;
        BODY(fA1, fB1, 1, fA0, fB0, STAGE(2, t + 2));
        BODY(fA0, fB0, 2, fA1, fB1, STAGE(3, t + 3));
        BODY(fA1, fB1, 3, fA0, fB0, STAGE(0, t + 4));
        BODY(fA0, fB0, 0, fA1, fB1, STAGE(1, t + 5));
    }
    // peeled tail: tiles 60..63
    BODY(fA1, fB1, 1, fA0, fB0, STAGE(2, 62));   // t=60
    BODY(fA0, fB0, 2, fA1, fB1, STAGE(3, 63));   // t=61
    BODY(fA1, fB1, 3, fA0, fB0, NOSTG);          // t=62 (reads tile 63)
    WAITV(0); BAR();                              // t=63: nothing outstanding
    MFMAC(fA1, fB1);

    // epilogue: C/D layout col=lane&15, row=quad*4+reg (m89-verified)
    #pragma unroll
    for (int m = 0; m < 8; ++m)
        #pragma unroll
        for (int n = 0; n < 4; ++n)
            #pragma unroll
            for (int j = 0; j < 4; ++j) {
                const int row = wm + m * 16 + q * 4 + j;
                const int col = wn + n * 16 + r;
                Cbase[(size_t)row * ND + col] = acc[m][n][j];
            }
}

// ---- Fallback (ws too small): fused fp32-staging kernel ----
#define LSTR 40
__global__ __launch_bounds__(256, 4) void fused_kernel(
    const float* __restrict__ A, const float* __restrict__ Bmat,
    float* __restrict__ C)
{
    __shared__ unsigned short Asf[BM][LSTR];
    __shared__ unsigned short Bsf[BN][LSTR];
    const int tid   = threadIdx.x;
    const int batch = blockIdx.z;
    const int row0  = blockIdx.y * BM;
    const int col0  = blockIdx.x * BN;
    const float* Abase = A    + (size_t)batch * MD * KD + (size_t)row0 * KD;
    const float* Bbase = Bmat + (size_t)batch * KD * ND + col0;
    float*       Cbase = C    + (size_t)batch * MD * ND + (size_t)row0 * ND + col0;
    const int a_row = tid >> 3, a_kc = (tid & 7) * 4;
    const int b_n = tid & 127, b_kh = (tid >> 7) * 16;
    const float* Bcol = Bbase + b_n;
    const int wave = tid >> 6, lane = tid & 63, q = lane >> 4, r = lane & 15;
    const int wm = (wave >> 1) * 64, wn = (wave & 1) * 64;
    f32x4 acc[4][4];
    #pragma unroll
    for (int i = 0; i < 4; ++i)
        #pragma unroll
        for (int j = 0; j < 4; ++j) acc[i][j] = (f32x4){0.f, 0.f, 0.f, 0.f};
    for (int k0 = 0; k0 < KD; k0 += 32) {
        #pragma unroll
        for (int i = 0; i < 4; ++i) {
            const int row = a_row + i * 32;
            const float4 v = *(const float4*)(Abase + (size_t)row * KD + k0 + a_kc);
            uint2 w; w.x = pk2(v.x, v.y); w.y = pk2(v.z, v.w);
            *(uint2*)&Asf[row][a_kc] = w;
        }
        #pragma unroll
        for (int h = 0; h < 2; ++h) {
            const int kb = b_kh + h * 8;
            float bv[8];
            #pragma unroll
            for (int j = 0; j < 8; ++j) bv[j] = Bcol[(size_t)(k0 + kb + j) * ND];
            uint4 w;
            w.x = pk2(bv[0], bv[1]); w.y = pk2(bv[2], bv[3]);
            w.z = pk2(bv[4], bv[5]); w.w = pk2(bv[6], bv[7]);
            *(uint4*)&Bsf[b_n][kb] = w;
        }
        __syncthreads();
        bf16x8 a_frag[4], b_frag[4];
        #pragma unroll
        for (int im = 0; im < 4; ++im)
            a_frag[im] = *(const bf16x8*)&Asf[wm + im * 16 + r][q * 8];
        #pragma unroll
        for (int in = 0; in < 4; ++in)
            b_frag[in] = *(const bf16x8*)&Bsf[wn + in * 16 + r][q * 8];
        #pragma unroll
        for (int im = 0; im < 4; ++im)
            #pragma unroll
            for (int in = 0; in < 4; ++in)
                acc[im][in] = MFMA16(a_frag[im], b_frag[in], acc[im][in]);
        __syncthreads();
    }
    #pragma unroll
    for (int im = 0; im < 4; ++im)
        #pragma unroll
        for (int in = 0; in < 4; ++in)
            #pragma unroll
            for (int j = 0; j < 4; ++j)
                Cbase[(size_t)(wm + im * 16 + q * 4 + j) * ND + wn + in * 16 + r]
                    = acc[im][in][j];
}

extern "C" void kernel_launch(void* const* d_in, const int* in_sizes, int n_in,
                              void* d_out, int out_size, void* d_ws, size_t ws_size,
                              hipStream_t stream) {
    const float* a = (const float*)d_in[0];
    const float* b = (const float*)d_in[1];
    float* out = (float*)d_out;

    const size_t abf_bytes = (size_t)NB * MD * KD * 2;   // 32 MB
    const size_t bt_bytes  = (size_t)NB * KD * ND * 2;   // 32 MB

    if (ws_size >= abf_bytes + bt_bytes) {
        unsigned short* Abf = (unsigned short*)d_ws;
        unsigned short* BT  = (unsigned short*)((char*)d_ws + abf_bytes);
        prep_kernel<<<dim3(NCAST + NB * (KD / 64) * (ND / 64)), dim3(256), 0, stream>>>(
            a, b, Abf, BT);
        const int nwg = (MD / 256) * (ND / 256) * NB;    // 256
        gemm256_kernel<<<dim3(nwg), dim3(512), 0, stream>>>(Abf, BT, out);
    } else {
        fused_kernel<<<dim3(ND / BN, MD / BM, NB), dim3(256), 0, stream>>>(a, b, out);
    }
}

// Round 7
// 232.484 us; speedup vs baseline: 1.0341x; 1.0341x over previous
//
#include <hip/hip_runtime.h>
#include <hip/hip_bf16.h>

#define NB   4
#define MD   2048
#define KD   2048
#define ND   2048

// fallback (fused) kernel tile
#define BM   128
#define BN   128

typedef short bf16x8 __attribute__((ext_vector_type(8)));
typedef float f32x4  __attribute__((ext_vector_type(4)));
typedef unsigned int u32;

#define MFMA16(a, b, c) __builtin_amdgcn_mfma_f32_16x16x32_bf16(a, b, c, 0, 0, 0)
#define BAR()    __builtin_amdgcn_s_barrier()
#define PRIO(n)  __builtin_amdgcn_s_setprio(n)
#define WAITV(n) asm volatile("s_waitcnt vmcnt(" #n ")" ::: "memory")
#define SCHEDB() __builtin_amdgcn_sched_barrier(0)

// pack two fp32 -> one dword of 2 bf16 (RNE)
__device__ __forceinline__ unsigned pk2(float lo, float hi) {
    union { __hip_bfloat162 h2; unsigned u; } c;
    c.h2 = __float22bfloat162_rn(make_float2(lo, hi));
    return c.u;
}

__device__ __forceinline__ void gload_lds16(const void* g, void* l) {
    __builtin_amdgcn_global_load_lds(
        (const __attribute__((address_space(1))) u32*)g,
        (__attribute__((address_space(3))) u32*)l,
        16, 0, 0);
}

// ---- Phase 1 (fused): A fp32->bf16 cast (8 elem/thread)  +  B -> BT bf16 ----
#define NCAST ((NB * MD * KD / 8) / 256)   // 8192 cast blocks (uint4 out/thread)

__global__ __launch_bounds__(256) void prep_kernel(
    const float* __restrict__ A, const float* __restrict__ B,
    unsigned short* __restrict__ Abf, unsigned short* __restrict__ BT)
{
    __shared__ float t[64][65];   // transpose tile; +1 pad -> <=2-way conflicts (free)
    const int tid = threadIdx.x;

    if (blockIdx.x < NCAST) {
        const size_t idx = (size_t)blockIdx.x * 256 + tid;   // uint4 (8 bf16) index
        const float4 v0 = ((const float4*)A)[2 * idx];
        const float4 v1 = ((const float4*)A)[2 * idx + 1];
        uint4 w;
        w.x = pk2(v0.x, v0.y); w.y = pk2(v0.z, v0.w);
        w.z = pk2(v1.x, v1.y); w.w = pk2(v1.z, v1.w);
        ((uint4*)Abf)[idx] = w;
        return;
    }
    const int bx  = blockIdx.x - NCAST;      // 0..4095
    const int b   = bx >> 10;                // batch (1024 tiles per batch)
    const int rem = bx & 1023;
    const int k0  = (rem & 31) * 64;
    const int n0  = (rem >> 5) * 64;

    const float* Bb = B + (size_t)b * KD * ND;
    const int rk = tid >> 4;                 // 0..15, +16/pass
    const int rn = (tid & 15) * 4;
    #pragma unroll
    for (int p = 0; p < 4; ++p) {
        const int kl = p * 16 + rk;
        const float4 v = *(const float4*)(Bb + (size_t)(k0 + kl) * ND + n0 + rn);
        t[kl][rn + 0] = v.x; t[kl][rn + 1] = v.y;
        t[kl][rn + 2] = v.z; t[kl][rn + 3] = v.w;
    }
    __syncthreads();
    const int wn = tid >> 2;                 // 0..63 (owns column n)
    const int wk = (tid & 3) * 16;           // 16 consecutive k
    float f[16];
    #pragma unroll
    for (int j = 0; j < 16; ++j) f[j] = t[wk + j][wn];
    uint4 w0, w1;
    w0.x = pk2(f[0], f[1]);   w0.y = pk2(f[2], f[3]);
    w0.z = pk2(f[4], f[5]);   w0.w = pk2(f[6], f[7]);
    w1.x = pk2(f[8], f[9]);   w1.y = pk2(f[10], f[11]);
    w1.z = pk2(f[12], f[13]); w1.w = pk2(f[14], f[15]);
    unsigned short* dst = BT + (size_t)b * ND * KD + (size_t)(n0 + wn) * KD + k0 + wk;
    *(uint4*)(dst) = w0;
    *(uint4*)(dst + 8) = w1;
}

// ---------------------------------------------------------------------------
// Phase 2 (round 7): 128x256 tile, BK=32, 8 waves of 64x64, 2 BLOCKS/CU.
//
// R2-R6 post-mortem: with 1 block/CU (128 KiB LDS, 244 unified regs), the 8
// barrier-locked waves have no independent work to fill the LDS-read phase;
// measured time = MFMA cycles + LDS cycles SUMMED in every schedule variant
// (43% util ceiling). The guide's m114 mechanism (implicit wave-level
// overlap from co-resident blocks) was structurally off. R7 restores it:
//   - per-wave output 64x64 -> acc 64 regs; __launch_bounds__(512,4) caps
//     unified regs at 128 -> 16 waves/CU (2 blocks).
//   - LDS (A 8KB + B 16KB) x 2 buffers = 48 KB -> 2 blocks fit.
//   - grid 512 = 2/CU exactly; XCD swizzle stays bijective.
//   - per-block schedule = R3's PROVEN fat-phase ledger per 32-k tile:
//     vmcnt(0)+bar; 8 ds_reads (before stage: R4 hazard rule); stage(t+1,
//     other buf); 16 indep MFMA. Stage targets the buffer last read one
//     barrier earlier (race-free, R3 ledger).
// Block 0's barrier/drain/LDS time is covered by block 1's MFMA phase.
// LDS layout (R6-verified, 0 conflicts): row pairs share a 128-B line
// [line][2 rows][4 slots of 16B]; physical slot = q ^ (line&3); gload dest
// linear tid*16, global source k pre-swizzled (rule #21).
// ---------------------------------------------------------------------------

#define TM 128
#define TN 256

// stage one 32-k tile: A 8 KB (1 round) + B 16 KB (2 rounds), 3 gloads/thread
#define STAGE(buf, tile) do {                                                 \
    gload_lds16(Abase + (size_t)sRow * KD + (size_t)(tile) * 32 + s_k,        \
                (char*)&LdsA[0][0] + (buf) * 8192 + tid * 16);                \
    gload_lds16(Bbase + (size_t)sRow * KD + (size_t)(tile) * 32 + s_k,        \
                (char*)&LdsB[0][0] + (buf) * 16384 + tid * 16);               \
    gload_lds16(Bbase + (size_t)(sRow + 128) * KD + (size_t)(tile) * 32 + s_k,\
                (char*)&LdsB[0][0] + (buf) * 16384 + 8192 + tid * 16);        \
} while (0)

#define READS(buf) do {                                                       \
    _Pragma("unroll")                                                         \
    for (int n_ = 0; n_ < 4; ++n_)                                            \
        fB[n_] = *(const bf16x8*)((const char*)&LdsB[0][0] + (buf) * 16384    \
                                  + bOff + n_ * 1024);                        \
    _Pragma("unroll")                                                         \
    for (int m_ = 0; m_ < 4; ++m_)                                            \
        fA[m_] = *(const bf16x8*)((const char*)&LdsA[0][0] + (buf) * 8192     \
                                  + aOff + m_ * 1024);                        \
} while (0)

#define MFMAC() do {                                                          \
    PRIO(1);                                                                  \
    _Pragma("unroll")                                                         \
    for (int m_ = 0; m_ < 4; ++m_)                                            \
        _Pragma("unroll")                                                     \
        for (int n_ = 0; n_ < 4; ++n_)                                        \
            acc[m_][n_] = MFMA16(fA[m_], fB[n_], acc[m_][n_]);                \
    PRIO(0);                                                                  \
} while (0)

#define NOSTG ((void)0)

#define BODY(buf, STG) do {                                                   \
    WAITV(0); BAR();                                                          \
    READS(buf);                                                               \
    SCHEDB();          /* keep stage below the reads (R4 hazard rule) */      \
    STG;                                                                      \
    MFMAC();                                                                  \
} while (0)

__global__ __launch_bounds__(512, 4) void gemm128x256_kernel(
    const unsigned short* __restrict__ Abf, const unsigned short* __restrict__ BT,
    float* __restrict__ C)
{
    __shared__ __align__(16) unsigned short LdsA[2][4096];   // 2 x 8 KB
    __shared__ __align__(16) unsigned short LdsB[2][8192];   // 2 x 16 KB

    const int tid = threadIdx.x;

    // XCD-bijective chunked swizzle: 512 wgs, 8 XCDs, 64 wgs/XCD.
    const int wg    = blockIdx.x;
    const int lin   = ((wg & 7) << 6) | (wg >> 3);
    const int batch = lin >> 7;               // 128 wgs per batch
    const int rem   = lin & 127;
    const int row0  = (rem >> 3) * TM;        // 16 M panels
    const int col0  = (rem & 7) * TN;         // 8 N panels

    const unsigned short* __restrict__ Abase =
        Abf + (size_t)batch * MD * KD + (size_t)row0 * KD;
    const unsigned short* __restrict__ Bbase =
        BT  + (size_t)batch * ND * KD + (size_t)col0 * KD;
    float* __restrict__ Cbase =
        C + (size_t)batch * MD * ND + (size_t)row0 * ND + col0;

    const int wave = tid >> 6;
    const int lane = tid & 63;
    const int q    = lane >> 4;              // 0..3 (16B slot within 64-B k-row)
    const int r    = lane & 15;              // 0..15
    const int wm   = (wave >> 2) * 64;       // 0 / 64
    const int wn   = (wave & 3)  * 64;       // 0,64,128,192

    // staging geometry: 512 thr x 16 B = 128 rows (paired lines) x 64 B
    const int sRow = ((tid >> 3) << 1) | ((tid >> 2) & 1);       // 0..127
    const int s_k  = ((tid & 3) ^ ((tid >> 3) & 3)) << 3;        // pre-swz src k

    // frag-read byte offsets (pair-line layout + slot XOR swizzle)
    const int RA   = wm + r;
    const int aOff = (RA >> 1) * 128 + (RA & 1) * 64 + ((q ^ ((RA >> 1) & 3)) * 16);
    const int RB   = wn + r;
    const int bOff = (RB >> 1) * 128 + (RB & 1) * 64 + ((q ^ ((RB >> 1) & 3)) * 16);

    f32x4 acc[4][4];
    #pragma unroll
    for (int m = 0; m < 4; ++m)
        #pragma unroll
        for (int n = 0; n < 4; ++n)
            acc[m][n] = (f32x4){0.f, 0.f, 0.f, 0.f};

    bf16x8 fA[4], fB[4];

    // prologue: stage tile 0 into buf 0
    STAGE(0, 0);

    for (int j = 0; j < 31; ++j) {           // tiles t=2j, 2j+1 (t <= 61)
        BODY(0, STAGE(1, 2 * j + 1));
        BODY(1, STAGE(0, 2 * j + 2));
    }
    BODY(0, STAGE(1, 63));                   // t=62
    BODY(1, NOSTG);                          // t=63

    // epilogue: C/D layout col=lane&15, row=quad*4+reg (m89-verified)
    #pragma unroll
    for (int m = 0; m < 4; ++m)
        #pragma unroll
        for (int n = 0; n < 4; ++n)
            #pragma unroll
            for (int j = 0; j < 4; ++j) {
                const int row = wm + m * 16 + q * 4 + j;
                const int col = wn + n * 16 + r;
                Cbase[(size_t)row * ND + col] = acc[m][n][j];
            }
}

// ---- Fallback (ws too small): fused fp32-staging kernel ----
#define LSTR 40
__global__ __launch_bounds__(256, 4) void fused_kernel(
    const float* __restrict__ A, const float* __restrict__ Bmat,
    float* __restrict__ C)
{
    __shared__ unsigned short Asf[BM][LSTR];
    __shared__ unsigned short Bsf[BN][LSTR];
    const int tid   = threadIdx.x;
    const int batch = blockIdx.z;
    const int row0  = blockIdx.y * BM;
    const int col0  = blockIdx.x * BN;
    const float* Abase = A    + (size_t)batch * MD * KD + (size_t)row0 * KD;
    const float* Bbase = Bmat + (size_t)batch * KD * ND + col0;
    float*       Cbase = C    + (size_t)batch * MD * ND + (size_t)row0 * ND + col0;
    const int a_row = tid >> 3, a_kc = (tid & 7) * 4;
    const int b_n = tid & 127, b_kh = (tid >> 7) * 16;
    const float* Bcol = Bbase + b_n;
    const int wave = tid >> 6, lane = tid & 63, q = lane >> 4, r = lane & 15;
    const int wm = (wave >> 1) * 64, wn = (wave & 1) * 64;
    f32x4 acc[4][4];
    #pragma unroll
    for (int i = 0; i < 4; ++i)
        #pragma unroll
        for (int j = 0; j < 4; ++j) acc[i][j] = (f32x4){0.f, 0.f, 0.f, 0.f};
    for (int k0 = 0; k0 < KD; k0 += 32) {
        #pragma unroll
        for (int i = 0; i < 4; ++i) {
            const int row = a_row + i * 32;
            const float4 v = *(const float4*)(Abase + (size_t)row * KD + k0 + a_kc);
            uint2 w; w.x = pk2(v.x, v.y); w.y = pk2(v.z, v.w);
            *(uint2*)&Asf[row][a_kc] = w;
        }
        #pragma unroll
        for (int h = 0; h < 2; ++h) {
            const int kb = b_kh + h * 8;
            float bv[8];
            #pragma unroll
            for (int j = 0; j < 8; ++j) bv[j] = Bcol[(size_t)(k0 + kb + j) * ND];
            uint4 w;
            w.x = pk2(bv[0], bv[1]); w.y = pk2(bv[2], bv[3]);
            w.z = pk2(bv[4], bv[5]); w.w = pk2(bv[6], bv[7]);
            *(uint4*)&Bsf[b_n][kb] = w;
        }
        __syncthreads();
        bf16x8 a_frag[4], b_frag[4];
        #pragma unroll
        for (int im = 0; im < 4; ++im)
            a_frag[im] = *(const bf16x8*)&Asf[wm + im * 16 + r][q * 8];
        #pragma unroll
        for (int in = 0; in < 4; ++in)
            b_frag[in] = *(const bf16x8*)&Bsf[wn + in * 16 + r][q * 8];
        #pragma unroll
        for (int im = 0; im < 4; ++im)
            #pragma unroll
            for (int in = 0; in < 4; ++in)
                acc[im][in] = MFMA16(a_frag[im], b_frag[in], acc[im][in]);
        __syncthreads();
    }
    #pragma unroll
    for (int im = 0; im < 4; ++im)
        #pragma unroll
        for (int in = 0; in < 4; ++in)
            #pragma unroll
            for (int j = 0; j < 4; ++j)
                Cbase[(size_t)(wm + im * 16 + q * 4 + j) * ND + wn + in * 16 + r]
                    = acc[im][in][j];
}

extern "C" void kernel_launch(void* const* d_in, const int* in_sizes, int n_in,
                              void* d_out, int out_size, void* d_ws, size_t ws_size,
                              hipStream_t stream) {
    const float* a = (const float*)d_in[0];
    const float* b = (const float*)d_in[1];
    float* out = (float*)d_out;

    const size_t abf_bytes = (size_t)NB * MD * KD * 2;   // 32 MB
    const size_t bt_bytes  = (size_t)NB * KD * ND * 2;   // 32 MB

    if (ws_size >= abf_bytes + bt_bytes) {
        unsigned short* Abf = (unsigned short*)d_ws;
        unsigned short* BT  = (unsigned short*)((char*)d_ws + abf_bytes);
        prep_kernel<<<dim3(NCAST + NB * (KD / 64) * (ND / 64)), dim3(256), 0, stream>>>(
            a, b, Abf, BT);
        const int nwg = (MD / TM) * (ND / TN) * NB;      // 512
        gemm128x256_kernel<<<dim3(nwg), dim3(512), 0, stream>>>(Abf, BT, out);
    } else {
        fused_kernel<<<dim3(ND / BN, MD / BM, NB), dim3(256), 0, stream>>>(a, b, out);
    }
}

// Round 8
// 228.486 us; speedup vs baseline: 1.0522x; 1.0175x over previous
//
#include <hip/hip_runtime.h>
#include <hip/hip_bf16.h>

#define NB   4
#define MD   2048
#define KD   2048
#define ND   2048

// fallback (fused) kernel tile
#define BM   128
#define BN   128

typedef short bf16x8 __attribute__((ext_vector_type(8)));
typedef float f32x4  __attribute__((ext_vector_type(4)));
typedef float f32x16 __attribute__((ext_vector_type(16)));
typedef unsigned int u32;

#define MFMA16(a, b, c) __builtin_amdgcn_mfma_f32_16x16x32_bf16(a, b, c, 0, 0, 0)
#define MFMA32(a, b, c) __builtin_amdgcn_mfma_f32_32x32x16_bf16(a, b, c, 0, 0, 0)
#define BAR()    __builtin_amdgcn_s_barrier()
#define PRIO(n)  __builtin_amdgcn_s_setprio(n)
#define WAITV(n) asm volatile("s_waitcnt vmcnt(" #n ")" ::: "memory")
#define SCHEDB() __builtin_amdgcn_sched_barrier(0)

// pack two fp32 -> one dword of 2 bf16 (RNE)
__device__ __forceinline__ unsigned pk2(float lo, float hi) {
    union { __hip_bfloat162 h2; unsigned u; } c;
    c.h2 = __float22bfloat162_rn(make_float2(lo, hi));
    return c.u;
}

__device__ __forceinline__ void gload_lds16(const void* g, void* l) {
    __builtin_amdgcn_global_load_lds(
        (const __attribute__((address_space(1))) u32*)g,
        (__attribute__((address_space(3))) u32*)l,
        16, 0, 0);
}

// ---- Phase 1 (fused): A fp32->bf16 cast (8 elem/thread)  +  B -> BT bf16 ----
#define NCAST ((NB * MD * KD / 8) / 256)   // 8192 cast blocks (uint4 out/thread)

__global__ __launch_bounds__(256) void prep_kernel(
    const float* __restrict__ A, const float* __restrict__ B,
    unsigned short* __restrict__ Abf, unsigned short* __restrict__ BT)
{
    __shared__ float t[64][65];   // transpose tile; +1 pad -> <=2-way conflicts (free)
    const int tid = threadIdx.x;

    if (blockIdx.x < NCAST) {
        const size_t idx = (size_t)blockIdx.x * 256 + tid;   // uint4 (8 bf16) index
        const float4 v0 = ((const float4*)A)[2 * idx];
        const float4 v1 = ((const float4*)A)[2 * idx + 1];
        uint4 w;
        w.x = pk2(v0.x, v0.y); w.y = pk2(v0.z, v0.w);
        w.z = pk2(v1.x, v1.y); w.w = pk2(v1.z, v1.w);
        ((uint4*)Abf)[idx] = w;
        return;
    }
    const int bx  = blockIdx.x - NCAST;      // 0..4095
    const int b   = bx >> 10;                // batch (1024 tiles per batch)
    const int rem = bx & 1023;
    const int k0  = (rem & 31) * 64;
    const int n0  = (rem >> 5) * 64;

    const float* Bb = B + (size_t)b * KD * ND;
    const int rk = tid >> 4;                 // 0..15, +16/pass
    const int rn = (tid & 15) * 4;
    #pragma unroll
    for (int p = 0; p < 4; ++p) {
        const int kl = p * 16 + rk;
        const float4 v = *(const float4*)(Bb + (size_t)(k0 + kl) * ND + n0 + rn);
        t[kl][rn + 0] = v.x; t[kl][rn + 1] = v.y;
        t[kl][rn + 2] = v.z; t[kl][rn + 3] = v.w;
    }
    __syncthreads();
    const int wn = tid >> 2;                 // 0..63 (owns column n)
    const int wk = (tid & 3) * 16;           // 16 consecutive k
    float f[16];
    #pragma unroll
    for (int j = 0; j < 16; ++j) f[j] = t[wk + j][wn];
    uint4 w0, w1;
    w0.x = pk2(f[0], f[1]);   w0.y = pk2(f[2], f[3]);
    w0.z = pk2(f[4], f[5]);   w0.w = pk2(f[6], f[7]);
    w1.x = pk2(f[8], f[9]);   w1.y = pk2(f[10], f[11]);
    w1.z = pk2(f[12], f[13]); w1.w = pk2(f[14], f[15]);
    unsigned short* dst = BT + (size_t)b * ND * KD + (size_t)(n0 + wn) * KD + k0 + wk;
    *(uint4*)(dst) = w0;
    *(uint4*)(dst + 8) = w1;
}

// ---------------------------------------------------------------------------
// Phase 2 (round 8): 256x256 tile, BK=64, 8 waves (2M x 4N), 32x32x16 MFMA,
// ONE fat phase per K-tile.
//
// R7 post-mortem: MFMA + LDS-read cycles SUM in every schedule tried (TLP
// via 2 blocks/CU did not de-phase them; R7 went 63->76 µs from higher
// per-CU LDS traffic). R8 minimizes the sum on the proven R3/R5 skeleton:
//  (a) v_mfma_32x32x16_bf16: pipe 2495 vs 2075 TF -> MFMA term 79.5k->66k
//      cyc/CU. Operand bytes/wave are geometry-fixed (unchanged LDS term).
//  (b) phantom-drain immunization (R4 lesson): ALL 24 ds_reads of tile t
//      precede the 8 global_load_lds of tile t+1 in program order
//      (sched_barrier-pinned regions: {reads+MFMA ks01} | STG | {MFMA ks23});
//      any compiler-inserted vmcnt before reads lands right after the
//      explicit vmcnt(0) -> no-op.
// Per tile: ESYNC(vmcnt0+bar) -> reads[B 8, A ks01 8] -> MFMA ks01 (16)
//           -> reads[A ks23 8] -> STG(t+1) -> MFMA ks23 (16).
// Race ledger (= R3's proven one): STG targets the buffer whose readers'
// ds_reads were consumed (lgkm dep) before those waves passed this tile's
// barrier; next tile's reads follow the next ESYNC's vmcnt(0)+barrier.
// Fragment maps: A/B lane = row (lane&31), k-half (lane>>5)*8 (mirrors the
// verified 16x16 pattern); C/D col=lane&31, row=(reg&3)+8*(reg>>2)+
// 4*(lane>>5) [m74/m101-verified].
// LDS [256][64] per buffer, slot-XOR swizzle (slot ^= row&7): 8 lanes per
// 16B slot, full-line coverage -> conflict-free (R5-measured 0).
// ---------------------------------------------------------------------------

// Stage one full 256x64 tile: 4 rounds of (64 rows x 128 B), 512 thr x 16 B.
#define STAGE4(dst, buf, base, tile) do {                                    \
    _Pragma("unroll")                                                        \
    for (int rr_ = 0; rr_ < 4; ++rr_) {                                      \
        gload_lds16((base) + (size_t)(rr_ * 64 + s_row) * KD                 \
                           + (size_t)(tile) * 64 + s_col,                    \
                    &dst[buf][0] + rr_ * 4096 + tid * 8);                    \
    }                                                                        \
} while (0)

#define NOSTG ((void)0)

// one K=64 tile (buffer p): reads -> MFMA ks01 -> reads -> STG -> MFMA ks23
#define PHASE(p, STG) do {                                                   \
    WAITV(0); BAR();                                                         \
    const char* Ab_ = ldsA + (p) * 32768;                                    \
    const char* Bb_ = ldsB + (p) * 32768;                                    \
    bf16x8 fB_[2][4], fA_[4][4];                                             \
    _Pragma("unroll")                                                        \
    for (int n_ = 0; n_ < 2; ++n_)                                           \
        _Pragma("unroll")                                                    \
        for (int ks_ = 0; ks_ < 4; ++ks_)                                    \
            fB_[n_][ks_] = *(const bf16x8*)(Bb_ + bRow[n_] + bSl[ks_]);      \
    _Pragma("unroll")                                                        \
    for (int m_ = 0; m_ < 4; ++m_)                                           \
        _Pragma("unroll")                                                    \
        for (int ks_ = 0; ks_ < 2; ++ks_)                                    \
            fA_[m_][ks_] = *(const bf16x8*)(Ab_ + aRow[m_] + aSl[ks_]);      \
    PRIO(1);                                                                 \
    _Pragma("unroll")                                                        \
    for (int ks_ = 0; ks_ < 2; ++ks_)                                        \
        _Pragma("unroll")                                                    \
        for (int m_ = 0; m_ < 4; ++m_)                                       \
            _Pragma("unroll")                                                \
            for (int n_ = 0; n_ < 2; ++n_)                                   \
                acc[m_][n_] = MFMA32(fA_[m_][ks_], fB_[n_][ks_], acc[m_][n_]);\
    PRIO(0);                                                                 \
    _Pragma("unroll")                                                        \
    for (int m_ = 0; m_ < 4; ++m_)                                           \
        _Pragma("unroll")                                                    \
        for (int ks_ = 2; ks_ < 4; ++ks_)                                    \
            fA_[m_][ks_] = *(const bf16x8*)(Ab_ + aRow[m_] + aSl[ks_]);      \
    SCHEDB();                                                                \
    STG;                                                                     \
    SCHEDB();                                                                \
    PRIO(1);                                                                 \
    _Pragma("unroll")                                                        \
    for (int ks_ = 2; ks_ < 4; ++ks_)                                        \
        _Pragma("unroll")                                                    \
        for (int m_ = 0; m_ < 4; ++m_)                                       \
            _Pragma("unroll")                                                \
            for (int n_ = 0; n_ < 2; ++n_)                                   \
                acc[m_][n_] = MFMA32(fA_[m_][ks_], fB_[n_][ks_], acc[m_][n_]);\
    PRIO(0);                                                                 \
} while (0)

__global__ __launch_bounds__(512, 2) void gemm256_kernel(
    const unsigned short* __restrict__ Abf, const unsigned short* __restrict__ BT,
    float* __restrict__ C)
{
    __shared__ __align__(16) unsigned short As[2][16384];   // 2 x 32 KB
    __shared__ __align__(16) unsigned short Bs[2][16384];   // 2 x 32 KB

    const int tid = threadIdx.x;

    // XCD-bijective chunked swizzle: 256 wgs, 8 XCDs, 32 wgs/XCD.
    const int wg    = blockIdx.x;
    const int lin   = ((wg & 7) << 5) | (wg >> 3);
    const int batch = lin >> 6;
    const int rem   = lin & 63;
    const int row0  = (rem >> 3) * 256;
    const int col0  = (rem & 7) * 256;

    const unsigned short* __restrict__ Abase =
        Abf + (size_t)batch * MD * KD + (size_t)row0 * KD;
    const unsigned short* __restrict__ Bbase =
        BT  + (size_t)batch * ND * KD + (size_t)col0 * KD;
    float* __restrict__ Cbase =
        C + (size_t)batch * MD * ND + (size_t)row0 * ND + col0;

    const int wave = tid >> 6;
    const int lane = tid & 63;
    const int l31  = lane & 31;          // row within 32x32 frag
    const int hi   = lane >> 5;          // k-half selector
    const int wm   = (wave >> 2) * 128;  // 0 / 128
    const int wn   = (wave & 3)  * 64;   // 0,64,128,192

    // staging geometry: per round 512 thr x 16 B = 64 rows x 128 B
    const int s_row = tid >> 3;                            // 0..63
    const int s_col = ((tid & 7) ^ (s_row & 7)) * 8;       // pre-swizzled src col (elems)

    // frag-read byte offsets: row r, k-step ks -> r*128 + ((2ks+hi)^(r&7))*16
    const int rA = wm + l31, xA = rA & 7;
    const int rB = wn + l31, xB = rB & 7;
    int aRow[4], bRow[2], aSl[4], bSl[4];
    #pragma unroll
    for (int m = 0; m < 4; ++m) aRow[m] = (rA + m * 32) * 128;
    #pragma unroll
    for (int n = 0; n < 2; ++n) bRow[n] = (rB + n * 32) * 128;
    #pragma unroll
    for (int ks = 0; ks < 4; ++ks) {
        aSl[ks] = ((2 * ks + hi) ^ xA) * 16;
        bSl[ks] = ((2 * ks + hi) ^ xB) * 16;
    }

    const char* ldsA = (const char*)&As[0][0];
    const char* ldsB = (const char*)&Bs[0][0];

    f32x16 acc[4][2];
    #pragma unroll
    for (int m = 0; m < 4; ++m)
        #pragma unroll
        for (int n = 0; n < 2; ++n)
            acc[m][n] = (f32x16){0.f};

    // prologue: stage tile 0 into buf 0
    STAGE4(As, 0, Abase, 0);
    STAGE4(Bs, 0, Bbase, 0);

    for (int j = 0; j < 15; ++j) {       // tiles t=2j, 2j+1 (t <= 29)
        PHASE(0, { STAGE4(As, 1, Abase, 2 * j + 1); STAGE4(Bs, 1, Bbase, 2 * j + 1); });
        PHASE(1, { STAGE4(As, 0, Abase, 2 * j + 2); STAGE4(Bs, 0, Bbase, 2 * j + 2); });
    }
    PHASE(0, { STAGE4(As, 1, Abase, 31); STAGE4(Bs, 1, Bbase, 31); });   // t=30
    PHASE(1, NOSTG);                                                      // t=31

    // epilogue: 32x32 C/D layout col=lane&31, row=(reg&3)+8*(reg>>2)+4*hi
    #pragma unroll
    for (int m = 0; m < 4; ++m)
        #pragma unroll
        for (int n = 0; n < 2; ++n)
            #pragma unroll
            for (int rg = 0; rg < 16; ++rg) {
                const int row = wm + m * 32 + (rg & 3) + 8 * (rg >> 2) + 4 * hi;
                const int col = wn + n * 32 + l31;
                Cbase[(size_t)row * ND + col] = acc[m][n][rg];
            }
}

// ---- Fallback (ws too small): fused fp32-staging kernel ----
#define LSTR 40
__global__ __launch_bounds__(256, 4) void fused_kernel(
    const float* __restrict__ A, const float* __restrict__ Bmat,
    float* __restrict__ C)
{
    __shared__ unsigned short Asf[BM][LSTR];
    __shared__ unsigned short Bsf[BN][LSTR];
    const int tid   = threadIdx.x;
    const int batch = blockIdx.z;
    const int row0  = blockIdx.y * BM;
    const int col0  = blockIdx.x * BN;
    const float* Abase = A    + (size_t)batch * MD * KD + (size_t)row0 * KD;
    const float* Bbase = Bmat + (size_t)batch * KD * ND + col0;
    float*       Cbase = C    + (size_t)batch * MD * ND + (size_t)row0 * ND + col0;
    const int a_row = tid >> 3, a_kc = (tid & 7) * 4;
    const int b_n = tid & 127, b_kh = (tid >> 7) * 16;
    const float* Bcol = Bbase + b_n;
    const int wave = tid >> 6, lane = tid & 63, q = lane >> 4, r = lane & 15;
    const int wm = (wave >> 1) * 64, wn = (wave & 1) * 64;
    f32x4 acc[4][4];
    #pragma unroll
    for (int i = 0; i < 4; ++i)
        #pragma unroll
        for (int j = 0; j < 4; ++j) acc[i][j] = (f32x4){0.f, 0.f, 0.f, 0.f};
    for (int k0 = 0; k0 < KD; k0 += 32) {
        #pragma unroll
        for (int i = 0; i < 4; ++i) {
            const int row = a_row + i * 32;
            const float4 v = *(const float4*)(Abase + (size_t)row * KD + k0 + a_kc);
            uint2 w; w.x = pk2(v.x, v.y); w.y = pk2(v.z, v.w);
            *(uint2*)&Asf[row][a_kc] = w;
        }
        #pragma unroll
        for (int h = 0; h < 2; ++h) {
            const int kb = b_kh + h * 8;
            float bv[8];
            #pragma unroll
            for (int j = 0; j < 8; ++j) bv[j] = Bcol[(size_t)(k0 + kb + j) * ND];
            uint4 w;
            w.x = pk2(bv[0], bv[1]); w.y = pk2(bv[2], bv[3]);
            w.z = pk2(bv[4], bv[5]); w.w = pk2(bv[6], bv[7]);
            *(uint4*)&Bsf[b_n][kb] = w;
        }
        __syncthreads();
        bf16x8 a_frag[4], b_frag[4];
        #pragma unroll
        for (int im = 0; im < 4; ++im)
            a_frag[im] = *(const bf16x8*)&Asf[wm + im * 16 + r][q * 8];
        #pragma unroll
        for (int in = 0; in < 4; ++in)
            b_frag[in] = *(const bf16x8*)&Bsf[wn + in * 16 + r][q * 8];
        #pragma unroll
        for (int im = 0; im < 4; ++im)
            #pragma unroll
            for (int in = 0; in < 4; ++in)
                acc[im][in] = MFMA16(a_frag[im], b_frag[in], acc[im][in]);
        __syncthreads();
    }
    #pragma unroll
    for (int im = 0; im < 4; ++im)
        #pragma unroll
        for (int in = 0; in < 4; ++in)
            #pragma unroll
            for (int j = 0; j < 4; ++j)
                Cbase[(size_t)(wm + im * 16 + q * 4 + j) * ND + wn + in * 16 + r]
                    = acc[im][in][j];
}

extern "C" void kernel_launch(void* const* d_in, const int* in_sizes, int n_in,
                              void* d_out, int out_size, void* d_ws, size_t ws_size,
                              hipStream_t stream) {
    const float* a = (const float*)d_in[0];
    const float* b = (const float*)d_in[1];
    float* out = (float*)d_out;

    const size_t abf_bytes = (size_t)NB * MD * KD * 2;   // 32 MB
    const size_t bt_bytes  = (size_t)NB * KD * ND * 2;   // 32 MB

    if (ws_size >= abf_bytes + bt_bytes) {
        unsigned short* Abf = (unsigned short*)d_ws;
        unsigned short* BT  = (unsigned short*)((char*)d_ws + abf_bytes);
        prep_kernel<<<dim3(NCAST + NB * (KD / 64) * (ND / 64)), dim3(256), 0, stream>>>(
            a, b, Abf, BT);
        const int nwg = (MD / 256) * (ND / 256) * NB;    // 256
        gemm256_kernel<<<dim3(nwg), dim3(512), 0, stream>>>(Abf, BT, out);
    } else {
        fused_kernel<<<dim3(ND / BN, MD / BM, NB), dim3(256), 0, stream>>>(a, b, out);
    }
}